// Round 14
// baseline (570.250 us; speedup 1.0000x reference)
//
#include <hip/hip_runtime.h>
#include <hip/hip_bf16.h>
#include <cstdint>
#include <cstddef>

#define B_  256
#define Z_  512
#define H_  2048
#define T_  16
#define H3_ 6144

using short8  = __attribute__((ext_vector_type(8))) short;
using bf16x8  = __attribute__((ext_vector_type(8))) __bf16;
using f32x4   = __attribute__((ext_vector_type(4))) float;
using f32x16  = __attribute__((ext_vector_type(16))) float;

__device__ __forceinline__ f32x4 mfma_bf16(short8 a, short8 b, f32x4 c) {
  return __builtin_amdgcn_mfma_f32_16x16x32_bf16(
      __builtin_bit_cast(bf16x8, a), __builtin_bit_cast(bf16x8, b), c, 0, 0, 0);
}
__device__ __forceinline__ f32x16 mfma_bf16_32(short8 a, short8 b, f32x16 c) {
  return __builtin_amdgcn_mfma_f32_32x32x16_bf16(
      __builtin_bit_cast(bf16x8, a), __builtin_bit_cast(bf16x8, b), c, 0, 0, 0);
}

__device__ __forceinline__ unsigned short f2bf(float f) {
  unsigned int u = __builtin_bit_cast(unsigned int, f);
  u = (u + 0x7FFFu + ((u >> 16) & 1u)) >> 16;
  return (unsigned short)u;
}

__device__ __forceinline__ float sigmoidf_(float x) { return 1.0f / (1.0f + __expf(-x)); }

// LDS XOR swizzles. 64-wide rows (8x16B chunks) and 128-wide rows (16 chunks).
__device__ __forceinline__ int swz(int row, int chunk) {
  return row * 64 + ((chunk ^ (row & 7)) << 3);    // ushort element offset
}
__device__ __forceinline__ int swz128(int row, int chunk) {
  return row * 128 + ((chunk ^ (row & 7)) << 3);   // ushort element offset
}

// ---------------------------------------------------------------------------
// GRU step v11: 1024 threads, 16 waves = (k-slice 8) x (gate-pair 2),
// 4 waves/SIMD for latency hiding (the axis all prior variants lacked).
// Tile M=64 x 128 gate-cols, grid 256, BK=128 double-buffer, 1 bar/chunk
// (STAGE(b) -> bar -> LDSET(next) -> COMP(b); reuse-safe per step10 proof).
// Per wave per chunk: 4 LDS frag reads + 4 mfma (1.0 reads/mfma).
// 8-way cross-slice reduce, one tile at a time (57KB overlay, 8 barriers).
// XCD swizzle: xcd = colgrp % 8; a colgroup's 4 m-sharers are co-XCD.
// ---------------------------------------------------------------------------
__global__ __launch_bounds__(1024, 4) void gru_step11(
    const unsigned short* __restrict__ A, int K,
    const unsigned short* __restrict__ Wr,
    const unsigned short* __restrict__ Wz,
    const unsigned short* __restrict__ Wn,
    const unsigned short* __restrict__ Whn,
    const float* __restrict__ cr, const float* __restrict__ cz,
    const float* __restrict__ cn, const float* __restrict__ chn,
    float hn_scale,
    const float* __restrict__ h_old,
    float* __restrict__ h_new,
    unsigned short* __restrict__ h_hist)
{
  // per buffer: A 64x128 (16KB) at [0,8192); W 128x128 (32KB) at [8192,24576)
  __shared__ __align__(16) unsigned short sbuf[2][24576];   // 96 KB dbuf
  float* red  = (float*)sbuf;   // [14][16][64] overlay (reduce, 57KB)
  float* LDSf = (float*)sbuf;   // [4][64][33] overlay (exchange)
  const int bid = blockIdx.x, tid = threadIdx.x;
  const int xcd = bid & 7, rst = bid >> 3;
  const int m_idx = rst & 3, gg = rst >> 2;
  const int grp = gg * 8 + xcd;            // [0,64) h-col group
  const int m0 = m_idx * 64;
  const int gh0 = grp * 32;                // h-col base
  const int wave = tid >> 6, lane = tid & 63;
  const int sid = wave & 7, gp = wave >> 3;
  const int lh = lane >> 5, l31 = lane & 31;

  // staging maps (1024 thr): A: 1 dwordx4/thread (64 rows x 16 chunks);
  //                          W: 2 dwordx4/thread (128 rows x 16 chunks).
  const int arow = tid >> 4, ac = tid & 15;
  const int wrow = tid >> 3, wc0 = (tid & 7) * 2;
  const unsigned short* wsrc =
      (wrow < 32) ? Wr : (wrow < 64) ? Wz : (wrow < 96) ? Wn : Whn; // wave-uniform
  const size_t aoff = (size_t)(m0 + arow) * K;
  const size_t woff = (size_t)(gh0 + (wrow & 31)) * K;
  const int ad0 = swz128(arow, ac);
  const int wd0 = 8192 + swz128(wrow, wc0 + 0);
  const int wd1 = 8192 + swz128(wrow, wc0 + 1);

  uint4 Ra0, Rw0, Rw1;
#define LDSET(k0)                                              \
  {                                                            \
    const int kk_ = (k0);                                      \
    Ra0 = *(const uint4*)(A    + aoff + kk_ + ac * 8);         \
    Rw0 = *(const uint4*)(wsrc + woff + kk_ + (wc0    ) * 8);  \
    Rw1 = *(const uint4*)(wsrc + woff + kk_ + (wc0 + 1) * 8);  \
  }
#define STAGE(b)                                               \
  {                                                            \
    unsigned short* p_ = sbuf[b];                              \
    *(uint4*)(p_ + ad0) = Ra0;                                 \
    *(uint4*)(p_ + wd0) = Rw0;                                 \
    *(uint4*)(p_ + wd1) = Rw1;                                 \
  }

  f32x16 a00 = {}, a01 = {}, a10 = {}, a11 = {};  // [mh][gate-of-pair]
  const int g0r = gp * 64, g1r = gp * 64 + 32;    // gate rows in W region

#define COMP(b)                                                            \
  {                                                                        \
    const unsigned short* p_ = sbuf[b];                                    \
    const int ch = sid * 2 + lh;                                           \
    short8 af0 = *(const short8*)(p_ + swz128(l31, ch));                   \
    short8 af1 = *(const short8*)(p_ + swz128(32 + l31, ch));              \
    short8 wf0 = *(const short8*)(p_ + 8192 + swz128(g0r + l31, ch));      \
    short8 wf1 = *(const short8*)(p_ + 8192 + swz128(g1r + l31, ch));      \
    a00 = mfma_bf16_32(af0, wf0, a00);                                     \
    a01 = mfma_bf16_32(af0, wf1, a01);                                     \
    a10 = mfma_bf16_32(af1, wf0, a10);                                     \
    a11 = mfma_bf16_32(af1, wf1, a11);                                     \
  }

  const int nIter = K >> 7;     // 128-K chunks: 16 (K=2048) or 4 (K=512)
  LDSET(0);
  for (int it = 0; it < nIter; ++it) {
    const int b = it & 1;
    STAGE(b);
    __syncthreads();
    if (it + 1 < nIter) LDSET((it + 1) << 7);
    COMP(b);
  }
#undef LDSET
#undef STAGE
#undef COMP

  // ---- 8-way cross-slice reduce, one register tile at a time ----
  __syncthreads();              // all COMP done; staging LDS now dead
#define RED(accv)                                                          \
  {                                                                        \
    if (sid != 0) {                                                        \
      float* rp = red + ((sid - 1) * 2 + gp) * 1024;                       \
      _Pragma("unroll")                                                    \
      for (int r = 0; r < 16; ++r) rp[r * 64 + lane] = accv[r];            \
    }                                                                      \
    __syncthreads();                                                       \
    if (sid == 0) {                                                        \
      _Pragma("unroll")                                                    \
      for (int ss = 0; ss < 7; ++ss) {                                     \
        const float* rp = red + (ss * 2 + gp) * 1024;                      \
        _Pragma("unroll")                                                  \
        for (int r = 0; r < 16; ++r) accv[r] += rp[r * 64 + lane];         \
      }                                                                    \
    }                                                                      \
    __syncthreads();                                                       \
  }
  RED(a00)
  RED(a01)
  RED(a10)
  RED(a11)
#undef RED

  if (sid == 0) {
    // gate exchange: C layout col=lane&31, row=(reg&3)+8*(reg>>2)+4*(lane>>5)
    const int gA2 = gp * 2, gB2 = gp * 2 + 1;
#pragma unroll
    for (int r = 0; r < 16; ++r) {
      const int trow = (r & 3) + 8 * (r >> 2) + 4 * lh;
      LDSf[(gA2 * 64 + trow     ) * 33 + l31] = a00[r];
      LDSf[(gB2 * 64 + trow     ) * 33 + l31] = a01[r];
      LDSf[(gA2 * 64 + 32 + trow) * 33 + l31] = a10[r];
      LDSf[(gB2 * 64 + 32 + trow) * 33 + l31] = a11[r];
    }
  }
  __syncthreads();
  {
    const int row = tid >> 4, c0 = (tid & 15) * 2;
    const int grow = m0 + row;
#pragma unroll
    for (int j = 0; j < 2; ++j) {
      const int col = c0 + j;
      const int gcol = gh0 + col;
      const float R   = sigmoidf_(LDSf[(0 * 64 + row) * 33 + col] + cr[gcol]);
      const float U   = sigmoidf_(LDSf[(1 * 64 + row) * 33 + col] + cz[gcol]);
      const float HNv = hn_scale * LDSf[(3 * 64 + row) * 33 + col] + chn[gcol];
      const float Nv  = tanhf(LDSf[(2 * 64 + row) * 33 + col] + cn[gcol] + R * HNv);
      const float ho  = h_old ? h_old[(size_t)grow * H_ + gcol] : 0.0f;
      const float hv  = (1.0f - U) * Nv + U * ho;
      h_new[(size_t)grow * H_ + gcol]  = hv;
      h_hist[(size_t)grow * H_ + gcol] = f2bf(hv);
    }
  }
}

// ---------------------------------------------------------------------------
// 64x64-tile bf16 GEMM core, C = A @ B^T (+add)(+bias). 4 waves of 32x32.
// ---------------------------------------------------------------------------
__device__ __forceinline__ void dev_gemm64core(
    unsigned short* sA, unsigned short* sB,
    const unsigned short* __restrict__ A,
    const unsigned short* __restrict__ Bw,
    int K,
    const float* __restrict__ addsrc, int add_ld,
    const float* __restrict__ bias,
    unsigned short* __restrict__ out_bf,
    float* __restrict__ out_f, int ldo, int mi, int ni)
{
  const int tid  = threadIdx.x;
  const int m0   = mi * 64, n0 = ni * 64;
  const int wave = tid >> 6, lane = tid & 63;
  const int wr = wave & 1, wc = wave >> 1;
  const int q = lane >> 4, c16 = lane & 15;
  const int lr = tid >> 3, lc8 = tid & 7;
  f32x4 acc[2][2] = {};
  const size_t aoff = (size_t)(m0 + lr) * K;
  const size_t boff = (size_t)(n0 + lr) * K;
  const size_t s32  = (size_t)32 * K;

  uint4 ra0, ra1, rb0, rb1;
  auto LOAD = [&](int k0) {
    const int gc = k0 + lc8 * 8;
    ra0 = *(const uint4*)(A  + aoff + gc);
    ra1 = *(const uint4*)(A  + aoff + s32 + gc);
    rb0 = *(const uint4*)(Bw + boff + gc);
    rb1 = *(const uint4*)(Bw + boff + s32 + gc);
  };

  const int nIter = K >> 6;
  LOAD(0);
  for (int it = 0; it < nIter; ++it) {
    __syncthreads();
    *(uint4*)(sA + swz(lr, lc8))      = ra0;
    *(uint4*)(sA + swz(lr + 32, lc8)) = ra1;
    *(uint4*)(sB + swz(lr, lc8))      = rb0;
    *(uint4*)(sB + swz(lr + 32, lc8)) = rb1;
    __syncthreads();
    if (it + 1 < nIter) LOAD((it + 1) << 6);
#pragma unroll
    for (int kk = 0; kk < 2; ++kk) {
      short8 af0 = *(const short8*)(sA + swz(wr * 32 + c16,      kk * 4 + q));
      short8 af1 = *(const short8*)(sA + swz(wr * 32 + 16 + c16, kk * 4 + q));
      short8 bf0 = *(const short8*)(sB + swz(wc * 32 + c16,      kk * 4 + q));
      short8 bf1 = *(const short8*)(sB + swz(wc * 32 + 16 + c16, kk * 4 + q));
      acc[0][0] = mfma_bf16(af0, bf0, acc[0][0]);
      acc[0][1] = mfma_bf16(af0, bf1, acc[0][1]);
      acc[1][0] = mfma_bf16(af1, bf0, acc[1][0]);
      acc[1][1] = mfma_bf16(af1, bf1, acc[1][1]);
    }
  }
#pragma unroll
  for (int i = 0; i < 2; ++i) {
#pragma unroll
    for (int j = 0; j < 2; ++j) {
#pragma unroll
      for (int v = 0; v < 4; ++v) {
        const int row = m0 + wr * 32 + i * 16 + q * 4 + v;
        const int col = n0 + wc * 32 + j * 16 + c16;
        float val = acc[i][j][v];
        if (addsrc) val += addsrc[(size_t)row * add_ld + col];
        if (bias)   val += bias[col];
        if (out_f)  out_f[(size_t)row * ldo + col] = val;
        if (out_bf) out_bf[(size_t)row * ldo + col] = f2bf(val);
      }
    }
  }
}

// all 3 W_comb GEMMs in one launch. Grid (32, 96): g = y>>5, ni = y&31.
__global__ __launch_bounds__(256) void gemm_wsum(
    const unsigned short* __restrict__ w_ih_q,
    const unsigned short* __restrict__ lin_wT_q,
    const float* __restrict__ w_hh,
    unsigned short* __restrict__ Wsum_r,
    unsigned short* __restrict__ Wsum_z,
    unsigned short* __restrict__ Wn_c)
{
  __shared__ unsigned short sA[64 * 64];
  __shared__ unsigned short sB[64 * 64];
  const int g = blockIdx.y >> 5, ni = blockIdx.y & 31;
  const float* adds = (g < 2) ? (w_hh + (size_t)g * H_ * H_) : nullptr;
  unsigned short* outw = (g == 0) ? Wsum_r : (g == 1) ? Wsum_z : Wn_c;
  dev_gemm64core(sA, sB, w_ih_q + (size_t)g * H_ * Z_, lin_wT_q, Z_,
                 adds, H_, nullptr, outw, nullptr, H_, blockIdx.x, ni);
}

// outs GEMM, grid (64, 8).
__global__ __launch_bounds__(256) void gemm_bt64(
    const unsigned short* __restrict__ A,
    const unsigned short* __restrict__ Bw,
    int K,
    const float* __restrict__ bias,
    float* __restrict__ out_f, int ldo)
{
  __shared__ unsigned short sA[64 * 64];
  __shared__ unsigned short sB[64 * 64];
  dev_gemm64core(sA, sB, A, Bw, K, nullptr, 0, bias, nullptr, out_f, ldo,
                 blockIdx.x, blockIdx.y);
}

// ---------------------------------------------------------------------------
// x0 = (z @ fc_w^T) * inv_sigma + fc_b, inv_sigma computed inline from t2.
// WG tile 32x64. Grid (8, 8).
// ---------------------------------------------------------------------------
__global__ __launch_bounds__(256) void x0_sig(
    const unsigned short* __restrict__ A,
    const unsigned short* __restrict__ Bw,
    const float* __restrict__ t2,
    const float* __restrict__ bias,
    unsigned short* __restrict__ out_bf)
{
  __shared__ unsigned short sA[32 * 64];
  __shared__ unsigned short sB[64 * 64];
  __shared__ float red2[256];
  const int tid  = threadIdx.x;
  const int K = Z_;
  {
    float v0 = t2[tid], v1 = t2[tid + 256];
    red2[tid] = v0 * v0 + v1 * v1;
    __syncthreads();
    for (int s = 128; s > 0; s >>= 1) {
      if (tid < s) red2[tid] += red2[tid + s];
      __syncthreads();
    }
  }
  const float s2 = red2[0];
  const float scale = (sqrtf(s2) + 1e-12f) / s2;
  const int m0   = blockIdx.x * 32, n0 = blockIdx.y * 64;
  const int wave = tid >> 6, lane = tid & 63;
  const int wr = wave & 1, wc = wave >> 1;
  const int q = lane >> 4, c16 = lane & 15;
  const int lr = tid >> 3, lc8 = tid & 7;
  f32x4 acc0 = {}, acc1 = {};
  const size_t rowA  = (size_t)(m0 + lr) * K;
  const size_t rowB0 = (size_t)(n0 + lr) * K;
  const size_t rowB1 = (size_t)(n0 + 32 + lr) * K;
  for (int k0 = 0; k0 < K; k0 += 64) {
    const int gc = k0 + lc8 * 8;
    uint4 ra  = *(const uint4*)(A  + rowA  + gc);
    uint4 rb0 = *(const uint4*)(Bw + rowB0 + gc);
    uint4 rb1 = *(const uint4*)(Bw + rowB1 + gc);
    __syncthreads();
    *(uint4*)(sA + swz(lr, lc8))      = ra;
    *(uint4*)(sB + swz(lr, lc8))      = rb0;
    *(uint4*)(sB + swz(32 + lr, lc8)) = rb1;
    __syncthreads();
#pragma unroll
    for (int kk = 0; kk < 2; ++kk) {
      const int arow = wr * 16 + c16;
      short8 af = *(const short8*)(sA + swz(arow, kk * 4 + q));
      const int brow = wc * 32 + c16;
      short8 b0 = *(const short8*)(sB + swz(brow, kk * 4 + q));
      acc0 = mfma_bf16(af, b0, acc0);
      short8 b1 = *(const short8*)(sB + swz(brow + 16, kk * 4 + q));
      acc1 = mfma_bf16(af, b1, acc1);
    }
  }
#pragma unroll
  for (int cf = 0; cf < 2; ++cf) {
    f32x4 a = cf ? acc1 : acc0;
#pragma unroll
    for (int v = 0; v < 4; ++v) {
      const int row = m0 + wr * 16 + q * 4 + v;
      const int col = n0 + wc * 32 + cf * 16 + c16;
      out_bf[(size_t)row * Z_ + col] = f2bf(a[v] * scale + bias[col]);
    }
  }
}

// ---------------------------------------------------------------------------
// Merged prep: quant (blocks 0..8575) | transq (8576..9599) |
// sigma1 (9600..9607) | dots+consts (9608..9991).  One launch, 9992 blocks.
// ---------------------------------------------------------------------------
__global__ __launch_bounds__(256) void prep_all(
    const float* __restrict__ z, const float* __restrict__ fc_w,
    const float* __restrict__ fc_u,
    const float* __restrict__ w_ih, const float* __restrict__ w_hh,
    const float* __restrict__ lin_w, const float* __restrict__ lin_b,
    const float* __restrict__ b_ih, const float* __restrict__ b_hh,
    unsigned short* __restrict__ z_q, unsigned short* __restrict__ fc_w_q,
    unsigned short* __restrict__ w_ih_q, unsigned short* __restrict__ w_hhn_q,
    unsigned short* __restrict__ lin_w_q, unsigned short* __restrict__ lin_wT_q,
    float* __restrict__ t1v,
    float* __restrict__ c0r, float* __restrict__ c0z, float* __restrict__ c0n,
    float* __restrict__ c1r, float* __restrict__ c1z, float* __restrict__ c1n,
    float* __restrict__ chn)
{
  __shared__ float sh[32 * 33];
  const int b = blockIdx.x, tid = threadIdx.x;
  if (b < 8576) {
    const int i = b * 256 + tid;
    const float4* src; ushort4* dst; int idx;
    if (i < 32768)        { src = (const float4*)z;     dst = (ushort4*)z_q;     idx = i; }
    else if (i < 98304)   { src = (const float4*)fc_w;  dst = (ushort4*)fc_w_q;  idx = i - 32768; }
    else if (i < 884736)  { src = (const float4*)w_ih;  dst = (ushort4*)w_ih_q;  idx = i - 98304; }
    else if (i < 1933312) { src = (const float4*)(w_hh + (size_t)2 * H_ * H_);
                            dst = (ushort4*)w_hhn_q;    idx = i - 884736; }
    else                  { src = (const float4*)lin_w; dst = (ushort4*)lin_w_q; idx = i - 1933312; }
    float4 v = src[idx];
    ushort4 o; o.x = f2bf(v.x); o.y = f2bf(v.y); o.z = f2bf(v.z); o.w = f2bf(v.w);
    dst[idx] = o;
  } else if (b < 9600) {
    const int tt = b - 8576;
    const int bx = tt >> 4, by = tt & 15;
    const int k0 = bx * 32, z0 = by * 32;
    const int tx = tid & 31, ty = tid >> 5;
#pragma unroll
    for (int j = 0; j < 4; ++j)
      sh[(ty + j * 8) * 33 + tx] = lin_w[(size_t)(z0 + ty + j * 8) * H_ + k0 + tx];
    __syncthreads();
#pragma unroll
    for (int j = 0; j < 4; ++j)
      lin_wT_q[(size_t)(k0 + ty + j * 8) * Z_ + z0 + tx] = f2bf(sh[tx * 33 + ty + j * 8]);
  } else if (b < 9608) {
    const int bb = b - 9600;
    const int lane = tid & 63, wv = tid >> 6;
    const int col = bb * 64 + lane;
    float s = 0.f;
    for (int r = wv * 128; r < wv * 128 + 128; ++r)
      s += fc_w[(size_t)r * Z_ + col] * fc_u[r];
    sh[wv * 64 + lane] = s;
    __syncthreads();
    if (wv == 0)
      t1v[col] = sh[lane] + sh[64 + lane] + sh[128 + lane] + sh[192 + lane];
  } else {
    const int bb = b - 9608;
    const int wave = tid >> 6, lane = tid & 63;
#pragma unroll
    for (int i = 0; i < 4; ++i) {
      int row = bb * 16 + wave * 4 + i;
      float s = 0.f;
      for (int c = lane; c < Z_; c += 64) s += w_ih[(size_t)row * Z_ + c] * lin_b[c];
#pragma unroll
      for (int off = 32; off > 0; off >>= 1) s += __shfl_down(s, off);
      if (lane == 0) {
        const int g = row >> 11, j = row & 2047;
        const float bi = b_ih[row], bh = b_hh[row];
        if (g == 0)      { c0r[j] = bi + bh; c1r[j] = bi + bh + s; }
        else if (g == 1) { c0z[j] = bi + bh; c1z[j] = bi + bh + s; }
        else             { c0n[j] = bi;      c1n[j] = bi + s;      chn[j] = bh; }
      }
    }
  }
}

// t2 = W @ normalize(t1); per-WG redundant norm recompute (t1 is 2KB, L2-hot).
__global__ void sigma2(const float* __restrict__ W, const float* __restrict__ t1,
                       float* __restrict__ t2) {
  __shared__ float red[256];
  const int tid = threadIdx.x;
  float p = 0.f;
  for (int c = tid; c < Z_; c += 256) { float v = t1[c]; p += v * v; }
  red[tid] = p;
  __syncthreads();
  for (int s = 128; s > 0; s >>= 1) {
    if (tid < s) red[tid] += red[tid + s];
    __syncthreads();
  }
  const float invn = 1.0f / (sqrtf(red[0]) + 1e-12f);
  const int lane = tid & 63, wv = tid >> 6;
  const int row = blockIdx.x * 4 + wv;
  float s = 0.f;
  for (int c = lane; c < Z_; c += 64) s += W[(size_t)row * Z_ + c] * t1[c];
#pragma unroll
  for (int off = 32; off > 0; off >>= 1) s += __shfl_down(s, off);
  if (lane == 0) t2[row] = s * invn;
}

// BN over batch per (t,z) + transpose [T,B,Z] -> [B,T,Z]. Grid (16, 8).
__global__ __launch_bounds__(256) void bn_k(const float* __restrict__ outs,
                                            float* __restrict__ y) {
  __shared__ float s_sum[4][64], s_sq[4][64], s_mean[64], s_inv[64];
  const int t = blockIdx.x, zb = blockIdx.y;
  const int zl = threadIdx.x & 63, bp = threadIdx.x >> 6;
  const int z = zb * 64 + zl;
  float sum = 0.f, sq = 0.f;
  for (int b = bp * 64; b < bp * 64 + 64; ++b) {
    float v = outs[(size_t)(t * 256 + b) * Z_ + z];
    sum += v; sq += v * v;
  }
  s_sum[bp][zl] = sum; s_sq[bp][zl] = sq;
  __syncthreads();
  if (bp == 0) {
    float S = s_sum[0][zl] + s_sum[1][zl] + s_sum[2][zl] + s_sum[3][zl];
    float Q = s_sq[0][zl] + s_sq[1][zl] + s_sq[2][zl] + s_sq[3][zl];
    float mean = S * (1.0f / 256.0f);
    float var  = Q * (1.0f / 256.0f) - mean * mean;
    s_mean[zl] = mean;
    s_inv[zl]  = rsqrtf(var + 1e-5f);
  }
  __syncthreads();
  const float mean = s_mean[zl], inv = s_inv[zl];
  for (int b = bp * 64; b < bp * 64 + 64; ++b) {
    float v = outs[(size_t)(t * 256 + b) * Z_ + z];
    y[(size_t)(b * T_ + t) * Z_ + z] = (v - mean) * inv;
  }
}

// ---------------------------------------------------------------------------
extern "C" void kernel_launch(void* const* d_in, const int* in_sizes, int n_in,
                              void* d_out, int out_size, void* d_ws, size_t ws_size,
                              hipStream_t stream) {
  const float* z     = (const float*)d_in[0];
  const float* fc_w  = (const float*)d_in[1];
  const float* fc_b  = (const float*)d_in[2];
  const float* fc_u  = (const float*)d_in[3];
  const float* w_ih  = (const float*)d_in[4];
  const float* w_hh  = (const float*)d_in[5];
  const float* b_ih  = (const float*)d_in[6];
  const float* b_hh  = (const float*)d_in[7];
  const float* lin_w = (const float*)d_in[8];
  const float* lin_b = (const float*)d_in[9];
  float* out = (float*)d_out;

  char* ws = (char*)d_ws;
  size_t off = 0;
  auto alloc = [&](size_t bytes) -> void* {
    off = (off + 255) & ~(size_t)255;
    void* p = ws + off;
    off += bytes;
    return p;
  };
  unsigned short* w_ih_q   = (unsigned short*)alloc((size_t)H3_ * Z_ * 2);
  unsigned short* w_hhn_q  = (unsigned short*)alloc((size_t)H_ * H_ * 2);
  unsigned short* lin_w_q  = (unsigned short*)alloc((size_t)Z_ * H_ * 2);
  unsigned short* lin_wT_q = (unsigned short*)alloc((size_t)Z_ * H_ * 2);
  unsigned short* fc_w_q   = (unsigned short*)alloc((size_t)Z_ * Z_ * 2);
  unsigned short* z_q      = (unsigned short*)alloc((size_t)B_ * Z_ * 2);
  unsigned short* x0_q     = (unsigned short*)alloc((size_t)B_ * Z_ * 2);
  unsigned short* Wsum_r   = (unsigned short*)alloc((size_t)H_ * H_ * 2);
  unsigned short* Wsum_z   = (unsigned short*)alloc((size_t)H_ * H_ * 2);
  unsigned short* Wn_c     = (unsigned short*)alloc((size_t)H_ * H_ * 2);
  unsigned short* Hhist    = (unsigned short*)alloc((size_t)T_ * B_ * H_ * 2);
  float* h_f32 = (float*)alloc((size_t)2 * B_ * H_ * 4);
  float* outs  = (float*)alloc((size_t)T_ * B_ * Z_ * 4);
  float* c0r = (float*)alloc(H_ * 4);
  float* c0z = (float*)alloc(H_ * 4);
  float* c0n = (float*)alloc(H_ * 4);
  float* c1r = (float*)alloc(H_ * 4);
  float* c1z = (float*)alloc(H_ * 4);
  float* c1n = (float*)alloc(H_ * 4);
  float* chn = (float*)alloc(H_ * 4);
  float* t1v = (float*)alloc(Z_ * 4);
  float* t2v = (float*)alloc(Z_ * 4);
  (void)in_sizes; (void)n_in; (void)out_size; (void)ws_size;

  prep_all<<<9992, 256, 0, stream>>>(
      z, fc_w, fc_u, w_ih, w_hh, lin_w, lin_b, b_ih, b_hh,
      z_q, fc_w_q, w_ih_q, w_hhn_q, lin_w_q, lin_wT_q,
      t1v, c0r, c0z, c0n, c1r, c1z, c1n, chn);
  sigma2<<<128, 256, 0, stream>>>(fc_w, t1v, t2v);
  x0_sig<<<dim3(8, 8), 256, 0, stream>>>(z_q, fc_w_q, t2v, fc_b, x0_q);

  // W_comb_g = w_ih_g @ lin_w (+ w_hh_g for r,z) -> bf16, 1 launch
  gemm_wsum<<<dim3(H_ / 64, 96), 256, 0, stream>>>(
      w_ih_q, lin_wT_q, w_hh, Wsum_r, Wsum_z, Wn_c);

  for (int t = 0; t < T_; ++t) {
    if (t == 0) {
      gru_step11<<<256, 1024, 0, stream>>>(
          x0_q, Z_,
          w_ih_q, w_ih_q + (size_t)H_ * Z_, w_ih_q + (size_t)2 * H_ * Z_,
          w_ih_q /* dummy, scaled by 0 */,
          c0r, c0z, c0n, chn, 0.0f, nullptr, h_f32, Hhist);
    } else {
      gru_step11<<<256, 1024, 0, stream>>>(
          Hhist + (size_t)(t - 1) * B_ * H_, H_,
          Wsum_r, Wsum_z, Wn_c, w_hhn_q,
          c1r, c1z, c1n, chn, 1.0f,
          h_f32 + (size_t)((t - 1) & 1) * B_ * H_,
          h_f32 + (size_t)(t & 1) * B_ * H_,
          Hhist + (size_t)t * B_ * H_);
    }
  }

  // outs[t*256+b][z] = Hhist[t][b] @ lin_w^T + lin_b   (f32)
  gemm_bt64<<<dim3(T_ * B_ / 64, Z_ / 64), 256, 0, stream>>>(
      Hhist, lin_w_q, H_, lin_b, outs, Z_);

  bn_k<<<dim3(T_, Z_ / 64), 256, 0, stream>>>(outs, out);
}

// Round 15
// 403.018 us; speedup vs baseline: 1.4149x; 1.4149x over previous
//
#include <hip/hip_runtime.h>
#include <hip/hip_bf16.h>
#include <cstdint>
#include <cstddef>

#define B_  256
#define Z_  512
#define H_  2048
#define T_  16
#define H3_ 6144

using short8  = __attribute__((ext_vector_type(8))) short;
using bf16x8  = __attribute__((ext_vector_type(8))) __bf16;
using f32x4   = __attribute__((ext_vector_type(4))) float;
using f32x16  = __attribute__((ext_vector_type(16))) float;

__device__ __forceinline__ f32x4 mfma_bf16(short8 a, short8 b, f32x4 c) {
  return __builtin_amdgcn_mfma_f32_16x16x32_bf16(
      __builtin_bit_cast(bf16x8, a), __builtin_bit_cast(bf16x8, b), c, 0, 0, 0);
}
__device__ __forceinline__ f32x16 mfma_bf16_32(short8 a, short8 b, f32x16 c) {
  return __builtin_amdgcn_mfma_f32_32x32x16_bf16(
      __builtin_bit_cast(bf16x8, a), __builtin_bit_cast(bf16x8, b), c, 0, 0, 0);
}

__device__ __forceinline__ unsigned short f2bf(float f) {
  unsigned int u = __builtin_bit_cast(unsigned int, f);
  u = (u + 0x7FFFu + ((u >> 16) & 1u)) >> 16;
  return (unsigned short)u;
}

__device__ __forceinline__ float sigmoidf_(float x) { return 1.0f / (1.0f + __expf(-x)); }

// LDS XOR swizzle: tiles are [rows][64] bf16 (128 B rows = 8x16B chunks).
__device__ __forceinline__ int swz(int row, int chunk) {
  return row * 64 + ((chunk ^ (row & 7)) << 3);   // ushort element offset
}

// ---------------------------------------------------------------------------
// GRU step v4. Tile: M=64 (m_idx 0..3) x 128 gate-cols (32 h-cols x 4 gates).
// Grid 256 (1 WG/CU), 512 thr, 8 waves = (gate 4) x (m-half 2); each wave one
// 32x32 tile via mfma_32x32x16. M=64 halves L2 weight re-reads vs v3
// (4 m-sharers instead of 8): per-XCD L2 traffic 40 -> 24 MB/step.
// XCD swizzle: xcd = colgrp % 8; a colgroup's 4 m-sharers are co-XCD.
// ---------------------------------------------------------------------------
__global__ __launch_bounds__(512, 1) void gru_step4(
    const unsigned short* __restrict__ A, int K,
    const unsigned short* __restrict__ Wr,
    const unsigned short* __restrict__ Wz,
    const unsigned short* __restrict__ Wn,
    const unsigned short* __restrict__ Whn,
    const float* __restrict__ cr, const float* __restrict__ cz,
    const float* __restrict__ cn, const float* __restrict__ chn,
    float hn_scale,
    const float* __restrict__ h_old,
    float* __restrict__ h_new,
    unsigned short* __restrict__ h_hist)
{
  // A region: 64x64 ush (8KB) at [0,4096); W region: 128x64 (16KB) at [4096,12288)
  __shared__ __align__(16) unsigned short sbuf[2][12288];   // 48 KB
  __shared__ float LDSf[4][64][33];                          // 33.8 KB exchange
  const int bid = blockIdx.x, tid = threadIdx.x;
  const int xcd = bid & 7, rst = bid >> 3;
  const int m_idx = rst & 3, gg = rst >> 2;
  const int grp = gg * 8 + xcd;            // [0,64) h-col group
  const int m0 = m_idx * 64;
  const int gh0 = grp * 32;                // h-col base
  const int wave = tid >> 6, lane = tid & 63;
  const int gate = wave & 3, mh = wave >> 2;
  const int lh = lane >> 5, l31 = lane & 31;

  // staging maps: A: 1 dwordx4/thread (64 rows x 8 chunks);
  //               W: 2 consecutive dwordx4/thread (128 rows x 8 chunks).
  const int arow = tid >> 3, achk = tid & 7;
  const int wrow = tid >> 2, wc0 = (tid & 3) * 2;
  const unsigned short* wsrc =
      (wrow < 32) ? Wr : (wrow < 64) ? Wz : (wrow < 96) ? Wn : Whn; // wave-uniform
  const size_t aoff = (size_t)(m0 + arow) * K + achk * 8;
  const size_t woff = (size_t)(gh0 + (wrow & 31)) * K + wc0 * 8;
  const int sa_d  = swz(arow, achk);
  const int sw_d0 = 4096 + swz(wrow, wc0 + 0);
  const int sw_d1 = 4096 + swz(wrow, wc0 + 1);

  uint4 Aa, Aw0, Aw1;   // prefetch set A (even chunks)
  uint4 Ba, Bw0, Bw1;   // prefetch set B (odd chunks)

#define LDSET(a, w0, w1, k0)                               \
  {                                                        \
    const int kk_ = (k0);                                  \
    a  = *(const uint4*)(A    + aoff + kk_);               \
    w0 = *(const uint4*)(wsrc + woff + kk_);               \
    w1 = *(const uint4*)(wsrc + woff + kk_ + 8);           \
  }
#define STAGE(s, a, w0, w1)                                \
  {                                                        \
    unsigned short* b_ = sbuf[s];                          \
    *(uint4*)(b_ + sa_d)  = a;                             \
    *(uint4*)(b_ + sw_d0) = w0;                            \
    *(uint4*)(b_ + sw_d1) = w1;                            \
  }

  f32x16 acc = {};
#define COMP(s)                                                            \
  {                                                                        \
    const unsigned short* b_ = sbuf[s];                                    \
    _Pragma("unroll")                                                      \
    for (int ks = 0; ks < 4; ++ks) {                                       \
      short8 af = *(const short8*)(b_ + swz(mh * 32 + l31, ks * 2 + lh));  \
      short8 wf = *(const short8*)(b_ + 4096 + swz(gate * 32 + l31, ks * 2 + lh)); \
      acc = mfma_bf16_32(af, wf, acc);                                     \
    }                                                                      \
  }

  const int nIter = K >> 6;     // 64-k chunks; 32 (K=2048) or 8 (K=512), even
  LDSET(Aa, Aw0, Aw1, 0);
  LDSET(Ba, Bw0, Bw1, 64);
  for (int it = 0; it < nIter; it += 2) {
    STAGE(0, Aa, Aw0, Aw1);
    __syncthreads();
    { const int kn = (it + 2 < nIter) ? ((it + 2) << 6) : 0;
      LDSET(Aa, Aw0, Aw1, kn); }
    COMP(0);
    STAGE(1, Ba, Bw0, Bw1);
    __syncthreads();
    { const int kn = (it + 3 < nIter) ? ((it + 3) << 6) : 64;
      LDSET(Ba, Bw0, Bw1, kn); }
    COMP(1);
  }
#undef LDSET
#undef STAGE
#undef COMP

  // ---- gate exchange: C layout col=lane&31, row=(reg&3)+8*(reg>>2)+4*(lane>>5)
#pragma unroll
  for (int reg = 0; reg < 16; ++reg) {
    const int trow = (reg & 3) + 8 * (reg >> 2) + 4 * lh;
    LDSf[gate][mh * 32 + trow][l31] = acc[reg];
  }
  __syncthreads();
  {
    const int row = tid >> 3, c0 = (tid & 7) * 4;
    const int grow = m0 + row;
#pragma unroll
    for (int j = 0; j < 4; ++j) {
      const int col = c0 + j;
      const int gcol = gh0 + col;
      const float R   = sigmoidf_(LDSf[0][row][col] + cr[gcol]);
      const float U   = sigmoidf_(LDSf[1][row][col] + cz[gcol]);
      const float HNv = hn_scale * LDSf[3][row][col] + chn[gcol];
      const float Nv  = tanhf(LDSf[2][row][col] + cn[gcol] + R * HNv);
      const float ho  = h_old ? h_old[(size_t)grow * H_ + gcol] : 0.0f;
      const float hv  = (1.0f - U) * Nv + U * ho;
      h_new[(size_t)grow * H_ + gcol]  = hv;
      h_hist[(size_t)grow * H_ + gcol] = f2bf(hv);
    }
  }
}

// ---------------------------------------------------------------------------
// Generic bf16 GEMM, C = A @ B^T (+add)(+bias)(*scale). WG tile 32x64.
// Grid = (M/32, N/64). Used only for the small x0 GEMM (M=256).
// ---------------------------------------------------------------------------
__global__ __launch_bounds__(256) void gemm_bt(
    const unsigned short* __restrict__ A,
    const unsigned short* __restrict__ Bw,
    int K,
    const float* __restrict__ addsrc, int add_ld,
    const float* __restrict__ bias,
    const float* __restrict__ scale_ptr,
    unsigned short* __restrict__ out_bf,
    float* __restrict__ out_f, int ldo)
{
  __shared__ unsigned short sA[32 * 64];
  __shared__ unsigned short sB[64 * 64];
  const int tid  = threadIdx.x;
  const int m0   = blockIdx.x * 32, n0 = blockIdx.y * 64;
  const int wave = tid >> 6, lane = tid & 63;
  const int wr = wave & 1, wc = wave >> 1;
  const int q = lane >> 4, c16 = lane & 15;
  const int lr = tid >> 3, lc8 = tid & 7;
  f32x4 acc0 = {}, acc1 = {};
  const size_t rowA  = (size_t)(m0 + lr) * K;
  const size_t rowB0 = (size_t)(n0 + lr) * K;
  const size_t rowB1 = (size_t)(n0 + 32 + lr) * K;
  for (int k0 = 0; k0 < K; k0 += 64) {
    const int gc = k0 + lc8 * 8;
    uint4 ra  = *(const uint4*)(A  + rowA  + gc);
    uint4 rb0 = *(const uint4*)(Bw + rowB0 + gc);
    uint4 rb1 = *(const uint4*)(Bw + rowB1 + gc);
    __syncthreads();
    *(uint4*)(sA + swz(lr, lc8))      = ra;
    *(uint4*)(sB + swz(lr, lc8))      = rb0;
    *(uint4*)(sB + swz(32 + lr, lc8)) = rb1;
    __syncthreads();
#pragma unroll
    for (int kk = 0; kk < 2; ++kk) {
      const int arow = wr * 16 + c16;
      short8 af = *(const short8*)(sA + swz(arow, kk * 4 + q));
      const int brow = wc * 32 + c16;
      short8 b0 = *(const short8*)(sB + swz(brow, kk * 4 + q));
      acc0 = mfma_bf16(af, b0, acc0);
      short8 b1 = *(const short8*)(sB + swz(brow + 16, kk * 4 + q));
      acc1 = mfma_bf16(af, b1, acc1);
    }
  }
  const float scale = scale_ptr ? *scale_ptr : 1.0f;
#pragma unroll
  for (int cf = 0; cf < 2; ++cf) {
    f32x4 a = cf ? acc1 : acc0;
#pragma unroll
    for (int v = 0; v < 4; ++v) {
      const int row = m0 + wr * 16 + q * 4 + v;
      const int col = n0 + wc * 32 + cf * 16 + c16;
      float val = a[v] * scale;
      if (addsrc) val += addsrc[(size_t)row * add_ld + col];
      if (bias)   val += bias[col];
      if (out_f)  out_f[(size_t)row * ldo + col] = val;
      if (out_bf) out_bf[(size_t)row * ldo + col] = f2bf(val);
    }
  }
}

// ---------------------------------------------------------------------------
// 64x64-tile bf16 GEMM, C = A @ B^T (+add)(+bias). Grid = (M/64, N/64).
// 4 waves of 32x32. Reg-prefetch pipeline.
// ---------------------------------------------------------------------------
__global__ __launch_bounds__(256) void gemm_bt64(
    const unsigned short* __restrict__ A,
    const unsigned short* __restrict__ Bw,
    int K,
    const float* __restrict__ addsrc, int add_ld,
    const float* __restrict__ bias,
    unsigned short* __restrict__ out_bf,
    float* __restrict__ out_f, int ldo)
{
  __shared__ unsigned short sA[64 * 64];
  __shared__ unsigned short sB[64 * 64];
  const int tid  = threadIdx.x;
  const int m0   = blockIdx.x * 64, n0 = blockIdx.y * 64;
  const int wave = tid >> 6, lane = tid & 63;
  const int wr = wave & 1, wc = wave >> 1;
  const int q = lane >> 4, c16 = lane & 15;
  const int lr = tid >> 3, lc8 = tid & 7;
  f32x4 acc[2][2] = {};
  const size_t aoff = (size_t)(m0 + lr) * K;
  const size_t boff = (size_t)(n0 + lr) * K;
  const size_t s32  = (size_t)32 * K;

  uint4 ra0, ra1, rb0, rb1;
  auto LOAD = [&](int k0) {
    const int gc = k0 + lc8 * 8;
    ra0 = *(const uint4*)(A  + aoff + gc);
    ra1 = *(const uint4*)(A  + aoff + s32 + gc);
    rb0 = *(const uint4*)(Bw + boff + gc);
    rb1 = *(const uint4*)(Bw + boff + s32 + gc);
  };

  const int nIter = K >> 6;
  LOAD(0);
  for (int it = 0; it < nIter; ++it) {
    __syncthreads();
    *(uint4*)(sA + swz(lr, lc8))      = ra0;
    *(uint4*)(sA + swz(lr + 32, lc8)) = ra1;
    *(uint4*)(sB + swz(lr, lc8))      = rb0;
    *(uint4*)(sB + swz(lr + 32, lc8)) = rb1;
    __syncthreads();
    if (it + 1 < nIter) LOAD((it + 1) << 6);
#pragma unroll
    for (int kk = 0; kk < 2; ++kk) {
      short8 af0 = *(const short8*)(sA + swz(wr * 32 + c16,      kk * 4 + q));
      short8 af1 = *(const short8*)(sA + swz(wr * 32 + 16 + c16, kk * 4 + q));
      short8 bf0 = *(const short8*)(sB + swz(wc * 32 + c16,      kk * 4 + q));
      short8 bf1 = *(const short8*)(sB + swz(wc * 32 + 16 + c16, kk * 4 + q));
      acc[0][0] = mfma_bf16(af0, bf0, acc[0][0]);
      acc[0][1] = mfma_bf16(af0, bf1, acc[0][1]);
      acc[1][0] = mfma_bf16(af1, bf0, acc[1][0]);
      acc[1][1] = mfma_bf16(af1, bf1, acc[1][1]);
    }
  }
#pragma unroll
  for (int i = 0; i < 2; ++i) {
#pragma unroll
    for (int j = 0; j < 2; ++j) {
#pragma unroll
      for (int v = 0; v < 4; ++v) {
        const int row = m0 + wr * 32 + i * 16 + q * 4 + v;
        const int col = n0 + wc * 32 + j * 16 + c16;
        float val = acc[i][j][v];
        if (addsrc) val += addsrc[(size_t)row * add_ld + col];
        if (bias)   val += bias[col];
        if (out_f)  out_f[(size_t)row * ldo + col] = val;
        if (out_bf) out_bf[(size_t)row * ldo + col] = f2bf(val);
      }
    }
  }
}

// ---------------------------------------------------------------------------
// merged quantization of all bf16 operands (one launch)
// ---------------------------------------------------------------------------
__global__ __launch_bounds__(256) void quant_all(
    const float* __restrict__ z, const float* __restrict__ fc_w,
    const float* __restrict__ w_ih, const float* __restrict__ w_hh,
    const float* __restrict__ lin_w,
    unsigned short* __restrict__ z_q, unsigned short* __restrict__ fc_w_q,
    unsigned short* __restrict__ w_ih_q, unsigned short* __restrict__ w_hhn_q,
    unsigned short* __restrict__ lin_w_q)
{
  const int i = blockIdx.x * 256 + threadIdx.x;
  if (i >= 2195456) return;
  const float4* src; ushort4* dst; int idx;
  if (i < 32768)        { src = (const float4*)z;     dst = (ushort4*)z_q;     idx = i; }
  else if (i < 98304)   { src = (const float4*)fc_w;  dst = (ushort4*)fc_w_q;  idx = i - 32768; }
  else if (i < 884736)  { src = (const float4*)w_ih;  dst = (ushort4*)w_ih_q;  idx = i - 98304; }
  else if (i < 1933312) { src = (const float4*)(w_hh + (size_t)2 * H_ * H_);
                          dst = (ushort4*)w_hhn_q;    idx = i - 884736; }
  else                  { src = (const float4*)lin_w; dst = (ushort4*)lin_w_q; idx = i - 1933312; }
  float4 v = src[idx];
  ushort4 o; o.x = f2bf(v.x); o.y = f2bf(v.y); o.z = f2bf(v.z); o.w = f2bf(v.w);
  dst[idx] = o;
}

// lin_w [512][2048] f32 -> lin_wT [2048][512] bf16
__global__ __launch_bounds__(256) void transq(const float* __restrict__ s,
                                              unsigned short* __restrict__ d) {
  __shared__ float tile[32][33];
  const int tx = threadIdx.x & 31, ty = threadIdx.x >> 5;
  const int k0 = blockIdx.x * 32, z0 = blockIdx.y * 32;
#pragma unroll
  for (int j = 0; j < 4; ++j)
    tile[ty + j * 8][tx] = s[(size_t)(z0 + ty + j * 8) * H_ + k0 + tx];
  __syncthreads();
#pragma unroll
  for (int j = 0; j < 4; ++j)
    d[(size_t)(k0 + ty + j * 8) * Z_ + z0 + tx] = f2bf(tile[tx][ty + j * 8]);
}

// t1 = W^T u.  grid 8, block 256 (4 waves x 128 rows each).
__global__ void sigma1(const float* __restrict__ W, const float* __restrict__ u,
                       float* __restrict__ t1) {
  __shared__ float part[4][64];
  const int lane = threadIdx.x & 63, wv = threadIdx.x >> 6;
  const int col = blockIdx.x * 64 + lane;
  float s = 0.f;
  for (int r = wv * 128; r < wv * 128 + 128; ++r)
    s += W[(size_t)r * Z_ + col] * u[r];
  part[wv][lane] = s;
  __syncthreads();
  if (wv == 0)
    t1[col] = part[0][lane] + part[1][lane] + part[2][lane] + part[3][lane];
}

__global__ void sigma1b(const float* __restrict__ t1, float* __restrict__ invn) {
  __shared__ float red[256];
  int t = threadIdx.x;
  float v0 = t1[t], v1 = t1[t + 256];
  red[t] = v0 * v0 + v1 * v1;
  __syncthreads();
  for (int s = 128; s > 0; s >>= 1) {
    if (t < s) red[t] += red[t + s];
    __syncthreads();
  }
  if (t == 0) invn[0] = 1.0f / (sqrtf(red[0]) + 1e-12f);
}

// t2 = W @ (t1 * invn).  grid 128, block 256 (wave per row).
__global__ void sigma2(const float* __restrict__ W, const float* __restrict__ t1,
                       const float* __restrict__ invn, float* __restrict__ t2) {
  const int lane = threadIdx.x & 63, wv = threadIdx.x >> 6;
  const int row = blockIdx.x * 4 + wv;
  float s = 0.f;
  for (int c = lane; c < Z_; c += 64) s += W[(size_t)row * Z_ + c] * t1[c];
#pragma unroll
  for (int off = 32; off > 0; off >>= 1) s += __shfl_down(s, off);
  if (lane == 0) t2[row] = s * invn[0];
}

__global__ void sigma3(const float* __restrict__ t2, float* __restrict__ inv_sig) {
  __shared__ float red[256];
  int t = threadIdx.x;
  float v0 = t2[t], v1 = t2[t + 256];
  red[t] = v0 * v0 + v1 * v1;
  __syncthreads();
  for (int s = 128; s > 0; s >>= 1) {
    if (t < s) red[t] += red[t + s];
    __syncthreads();
  }
  if (t == 0) {
    float s2  = red[0];
    float sig = s2 / (sqrtf(s2) + 1e-12f);
    inv_sig[0] = 1.0f / sig;
  }
}

// dvec[row] = dot(w_ih[row], lin_b) for row in [0, 6144)
__global__ __launch_bounds__(256) void dots_k(const float* __restrict__ w,
                                              const float* __restrict__ lb,
                                              float* __restrict__ dvec) {
  const int wave = threadIdx.x >> 6, lane = threadIdx.x & 63;
#pragma unroll
  for (int i = 0; i < 4; ++i) {
    int row = blockIdx.x * 16 + wave * 4 + i;
    float s = 0.f;
    for (int c = lane; c < Z_; c += 64) s += w[(size_t)row * Z_ + c] * lb[c];
#pragma unroll
    for (int off = 32; off > 0; off >>= 1) s += __shfl_down(s, off);
    if (lane == 0) dvec[row] = s;
  }
}

__global__ void consts_k(const float* __restrict__ b_ih, const float* __restrict__ b_hh,
                         const float* __restrict__ dvec,
                         float* __restrict__ c0r, float* __restrict__ c0z,
                         float* __restrict__ c0n,
                         float* __restrict__ c1r, float* __restrict__ c1z,
                         float* __restrict__ c1n, float* __restrict__ chn) {
  int j = blockIdx.x * 256 + threadIdx.x;
  float br = b_ih[j], bz = b_ih[H_ + j], bn = b_ih[2 * H_ + j];
  float hr = b_hh[j], hz = b_hh[H_ + j], hn = b_hh[2 * H_ + j];
  c0r[j] = br + hr; c0z[j] = bz + hz; c0n[j] = bn; chn[j] = hn;
  c1r[j] = br + hr + dvec[j];
  c1z[j] = bz + hz + dvec[H_ + j];
  c1n[j] = bn + dvec[2 * H_ + j];
}

// BN over batch per (t,z) + transpose [T,B,Z] -> [B,T,Z]. Grid (16, 8).
__global__ __launch_bounds__(256) void bn_k(const float* __restrict__ outs,
                                            float* __restrict__ y) {
  __shared__ float s_sum[4][64], s_sq[4][64], s_mean[64], s_inv[64];
  const int t = blockIdx.x, zb = blockIdx.y;
  const int zl = threadIdx.x & 63, bp = threadIdx.x >> 6;
  const int z = zb * 64 + zl;
  float sum = 0.f, sq = 0.f;
  for (int b = bp * 64; b < bp * 64 + 64; ++b) {
    float v = outs[(size_t)(t * 256 + b) * Z_ + z];
    sum += v; sq += v * v;
  }
  s_sum[bp][zl] = sum; s_sq[bp][zl] = sq;
  __syncthreads();
  if (bp == 0) {
    float S = s_sum[0][zl] + s_sum[1][zl] + s_sum[2][zl] + s_sum[3][zl];
    float Q = s_sq[0][zl] + s_sq[1][zl] + s_sq[2][zl] + s_sq[3][zl];
    float mean = S * (1.0f / 256.0f);
    float var  = Q * (1.0f / 256.0f) - mean * mean;
    s_mean[zl] = mean;
    s_inv[zl]  = rsqrtf(var + 1e-5f);
  }
  __syncthreads();
  const float mean = s_mean[zl], inv = s_inv[zl];
  for (int b = bp * 64; b < bp * 64 + 64; ++b) {
    float v = outs[(size_t)(t * 256 + b) * Z_ + z];
    y[(size_t)(b * T_ + t) * Z_ + z] = (v - mean) * inv;
  }
}

// ---------------------------------------------------------------------------
extern "C" void kernel_launch(void* const* d_in, const int* in_sizes, int n_in,
                              void* d_out, int out_size, void* d_ws, size_t ws_size,
                              hipStream_t stream) {
  const float* z     = (const float*)d_in[0];
  const float* fc_w  = (const float*)d_in[1];
  const float* fc_b  = (const float*)d_in[2];
  const float* fc_u  = (const float*)d_in[3];
  const float* w_ih  = (const float*)d_in[4];
  const float* w_hh  = (const float*)d_in[5];
  const float* b_ih  = (const float*)d_in[6];
  const float* b_hh  = (const float*)d_in[7];
  const float* lin_w = (const float*)d_in[8];
  const float* lin_b = (const float*)d_in[9];
  float* out = (float*)d_out;

  char* ws = (char*)d_ws;
  size_t off = 0;
  auto alloc = [&](size_t bytes) -> void* {
    off = (off + 255) & ~(size_t)255;
    void* p = ws + off;
    off += bytes;
    return p;
  };
  unsigned short* w_ih_q   = (unsigned short*)alloc((size_t)H3_ * Z_ * 2);
  unsigned short* w_hhn_q  = (unsigned short*)alloc((size_t)H_ * H_ * 2);
  unsigned short* lin_w_q  = (unsigned short*)alloc((size_t)Z_ * H_ * 2);
  unsigned short* lin_wT_q = (unsigned short*)alloc((size_t)Z_ * H_ * 2);
  unsigned short* fc_w_q   = (unsigned short*)alloc((size_t)Z_ * Z_ * 2);
  unsigned short* z_q      = (unsigned short*)alloc((size_t)B_ * Z_ * 2);
  unsigned short* x0_q     = (unsigned short*)alloc((size_t)B_ * Z_ * 2);
  unsigned short* Wsum_r   = (unsigned short*)alloc((size_t)H_ * H_ * 2);
  unsigned short* Wsum_z   = (unsigned short*)alloc((size_t)H_ * H_ * 2);
  unsigned short* Wn_c     = (unsigned short*)alloc((size_t)H_ * H_ * 2);
  unsigned short* Hhist    = (unsigned short*)alloc((size_t)T_ * B_ * H_ * 2);
  float* h_f32 = (float*)alloc((size_t)2 * B_ * H_ * 4);
  float* outs  = (float*)alloc((size_t)T_ * B_ * Z_ * 4);
  float* c0r = (float*)alloc(H_ * 4);
  float* c0z = (float*)alloc(H_ * 4);
  float* c0n = (float*)alloc(H_ * 4);
  float* c1r = (float*)alloc(H_ * 4);
  float* c1z = (float*)alloc(H_ * 4);
  float* c1n = (float*)alloc(H_ * 4);
  float* chn = (float*)alloc(H_ * 4);
  float* dvec = (float*)alloc(H3_ * 4);
  float* t1v = (float*)alloc(Z_ * 4);
  float* t2v = (float*)alloc(Z_ * 4);
  float* invn = (float*)alloc(256);
  float* invsig = (float*)alloc(256);
  (void)in_sizes; (void)n_in; (void)out_size; (void)ws_size;

  quant_all<<<dim3((2195456 + 255) / 256), 256, 0, stream>>>(
      z, fc_w, w_ih, w_hh, lin_w, z_q, fc_w_q, w_ih_q, w_hhn_q, lin_w_q);
  transq<<<dim3(64, 16), 256, 0, stream>>>(lin_w, lin_wT_q);
  sigma1<<<8, 256, 0, stream>>>(fc_w, fc_u, t1v);
  sigma1b<<<1, 256, 0, stream>>>(t1v, invn);
  sigma2<<<128, 256, 0, stream>>>(fc_w, t1v, invn, t2v);
  sigma3<<<1, 256, 0, stream>>>(t2v, invsig);
  dots_k<<<384, 256, 0, stream>>>(w_ih, lin_b, dvec);
  consts_k<<<8, 256, 0, stream>>>(b_ih, b_hh, dvec, c0r, c0z, c0n, c1r, c1z, c1n, chn);

  // x0 = (z @ fc_w^T) * inv_sigma + fc_b   -> bf16
  gemm_bt<<<dim3(B_ / 32, Z_ / 64), 256, 0, stream>>>(
      z_q, fc_w_q, Z_, nullptr, 0, fc_b, invsig, x0_q, nullptr, Z_);

  // W_comb_g = w_ih_g @ lin_w (+ w_hh_g for r,z) -> bf16 [2048][2048]
  for (int g = 0; g < 3; ++g) {
    const float* adds = (g < 2) ? (w_hh + (size_t)g * H_ * H_) : nullptr;
    unsigned short* outw = (g == 0) ? Wsum_r : (g == 1) ? Wsum_z : Wn_c;
    gemm_bt64<<<dim3(H_ / 64, H_ / 64), 256, 0, stream>>>(
        w_ih_q + (size_t)g * H_ * Z_, lin_wT_q, Z_, adds, H_, nullptr,
        outw, nullptr, H_);
  }

  for (int t = 0; t < T_; ++t) {
    if (t == 0) {
      gru_step4<<<256, 512, 0, stream>>>(
          x0_q, Z_,
          w_ih_q, w_ih_q + (size_t)H_ * Z_, w_ih_q + (size_t)2 * H_ * Z_,
          w_ih_q /* dummy, scaled by 0 */,
          c0r, c0z, c0n, chn, 0.0f, nullptr, h_f32, Hhist);
    } else {
      gru_step4<<<256, 512, 0, stream>>>(
          Hhist + (size_t)(t - 1) * B_ * H_, H_,
          Wsum_r, Wsum_z, Wn_c, w_hhn_q,
          c1r, c1z, c1n, chn, 1.0f,
          h_f32 + (size_t)((t - 1) & 1) * B_ * H_,
          h_f32 + (size_t)(t & 1) * B_ * H_,
          Hhist + (size_t)t * B_ * H_);
    }
  }

  // outs[t*256+b][z] = Hhist[t][b] @ lin_w^T + lin_b   (f32)
  gemm_bt64<<<dim3(T_ * B_ / 64, Z_ / 64), 256, 0, stream>>>(
      Hhist, lin_w_q, H_, nullptr, 0, lin_b, nullptr, outs, Z_);

  bn_k<<<dim3(T_, Z_ / 64), 256, 0, stream>>>(outs, out);
}